// Round 4
// baseline (1368.272 us; speedup 1.0000x reference)
//
#include <hip/hip_runtime.h>
#include <hip/hip_fp16.h>

#define DIMM 128
#define LEAKY_S 0.01f
#define EPS_BN 1e-5f

typedef _Float16 half8 __attribute__((ext_vector_type(8)));
typedef float f32x4 __attribute__((ext_vector_type(4)));

// ---------------------------------------------------------------------------
// Graph preprocessing: degree -> rowptr (3-phase parallel scan) -> CSR fill
// ---------------------------------------------------------------------------

__global__ __launch_bounds__(256) void k_deg(const int* __restrict__ dst, int* __restrict__ deg, int E, int N) {
    int i = blockIdx.x * 256 + threadIdx.x;
    if (i < E) {
        int d = dst[i];
        if ((unsigned)d < (unsigned)N) atomicAdd(&deg[d], 1);
    }
}

__global__ __launch_bounds__(256) void k_dinv(const int* __restrict__ deg, float* __restrict__ dinv, int N) {
    int i = blockIdx.x * 256 + threadIdx.x;
    if (i < N) dinv[i] = rsqrtf((float)(deg[i] + 1));   // +1 self-loop
}

__global__ __launch_bounds__(256) void k_scanA(const int* __restrict__ deg, int* __restrict__ bsum, int n) {
    __shared__ int ws[4];
    int tid = threadIdx.x, lane = tid & 63, wid = tid >> 6;
    int base = blockIdx.x * 1024;
    int s = 0;
    #pragma unroll
    for (int j = 0; j < 4; ++j) {
        int i = base + j * 256 + tid;
        if (i < n) s += deg[i];
    }
    #pragma unroll
    for (int off = 32; off > 0; off >>= 1) s += __shfl_down(s, (unsigned)off, 64);
    if (lane == 0) ws[wid] = s;
    __syncthreads();
    if (tid == 0) bsum[blockIdx.x] = ws[0] + ws[1] + ws[2] + ws[3];
}

__global__ __launch_bounds__(64) void k_scanB(const int* __restrict__ bsum, int* __restrict__ bofs,
                                              int* __restrict__ rowptr, int nb, int n) {
    if (threadIdx.x == 0) {
        int run = 0;
        for (int j = 0; j < nb; ++j) { bofs[j] = run; run += bsum[j]; }
        rowptr[n] = run;
    }
}

__global__ __launch_bounds__(1024) void k_scanC(const int* __restrict__ deg, const int* __restrict__ bofs,
                                                int* __restrict__ rowptr, int n) {
    __shared__ int wsum[16];
    int tid = threadIdx.x, lane = tid & 63, wid = tid >> 6;
    int i = blockIdx.x * 1024 + tid;
    int v = (i < n) ? deg[i] : 0;
    int s = v;
    #pragma unroll
    for (int off = 1; off < 64; off <<= 1) {
        int t = __shfl_up(s, (unsigned)off, 64);
        if (lane >= off) s += t;
    }
    if (lane == 63) wsum[wid] = s;
    __syncthreads();
    if (wid == 0 && lane < 16) {
        int ws = wsum[lane];
        #pragma unroll
        for (int off = 1; off < 16; off <<= 1) {
            int t = __shfl_up(ws, (unsigned)off, 64);
            if (lane >= off) ws += t;
        }
        wsum[lane] = ws;
    }
    __syncthreads();
    int woff = wid ? wsum[wid - 1] : 0;
    if (i < n) rowptr[i] = bofs[blockIdx.x] + woff + (s - v);
}

__global__ __launch_bounds__(256) void k_fill(const int* __restrict__ src, const int* __restrict__ dst,
                                              const int* __restrict__ rowptr, int* __restrict__ cursor,
                                              const float* __restrict__ dinv,
                                              int2* __restrict__ csr, int E, int N) {
    int i = blockIdx.x * 256 + threadIdx.x;
    if (i < E) {
        int d = dst[i], s = src[i];
        if ((unsigned)d < (unsigned)N && (unsigned)s < (unsigned)N) {
            int pos = atomicAdd(&cursor[d], 1);
            int idx = rowptr[d] + pos;
            csr[idx] = make_int2(s, __float_as_int(dinv[s] * dinv[d]));
        }
    }
}

// ---------------------------------------------------------------------------
// W prep: Wt16[l][n][k] = f16(W[l][k][n])
// ---------------------------------------------------------------------------

__global__ __launch_bounds__(256) void k_wprep(const float* __restrict__ Ws, __half* __restrict__ Wt) {
    int l = blockIdx.y;
    int i = blockIdx.x * 256 + threadIdx.x;
    int n = i >> 7, k = i & 127;
    Wt[(size_t)l * DIMM * DIMM + n * DIMM + k] = __float2half(Ws[(size_t)l * DIMM * DIMM + k * DIMM + n]);
}

// ---------------------------------------------------------------------------
// MFMA GEMM: out16[N,128] = f16( f16(affine(A)) @ f16(W) + b )
// A is fp32 (layer 0, identity affine) or fp16 (later layers, BN affine
// computed IN-KERNEL from stats of the previous k_agg -> k_bnfin launch gone).
// ---------------------------------------------------------------------------

__global__ __launch_bounds__(256) void k_gemm(const void* __restrict__ A, const __half* __restrict__ Wt,
                                              const float* __restrict__ bias,
                                              const float* __restrict__ stats, const float* __restrict__ gamma,
                                              const float* __restrict__ beta,
                                              __half* __restrict__ out, int N, int a_half, float inv_n) {
    __shared__ char smem[128 * 272];
    __shared__ float ssm[256];
    int tid = threadIdx.x;
    int lane = tid & 63, wid = tid >> 6;
    int quad = lane >> 4, lm = lane & 15;
    int row0 = blockIdx.x * 128;

    if (a_half && tid < 128) {
        float mu  = stats[tid] * inv_n;
        float var = stats[128 + tid] * inv_n - mu * mu;
        float a = gamma[tid] * rsqrtf(var + EPS_BN);
        ssm[tid]       = a;
        ssm[128 + tid] = beta[tid] - mu * a;
    }
    __syncthreads();

    {
        int seg = tid & 31;
        int col = seg * 4;
        float4 sc = make_float4(1.f, 1.f, 1.f, 1.f);
        float4 sh = make_float4(0.f, 0.f, 0.f, 0.f);
        if (a_half) {
            sc = *(const float4*)(ssm + col);
            sh = *(const float4*)(ssm + 128 + col);
        }
        const float*  Af = (const float*)A;
        const __half* Ah = (const __half*)A;
        for (int i = tid; i < 128 * 32; i += 256) {
            int r = i >> 5;
            int gr = row0 + r;
            float4 v = make_float4(0.f, 0.f, 0.f, 0.f);
            if (gr < N) {
                if (a_half) {
                    union { uint2 u; __half2 h2[2]; } ld;
                    ld.u = *(const uint2*)(Ah + (size_t)gr * DIMM + col);
                    float2 f0 = __half22float2(ld.h2[0]);
                    float2 f1 = __half22float2(ld.h2[1]);
                    v = make_float4(f0.x * sc.x + sh.x, f0.y * sc.y + sh.y,
                                    f1.x * sc.z + sh.z, f1.y * sc.w + sh.w);
                } else {
                    v = *(const float4*)(Af + (size_t)gr * DIMM + col);
                }
            }
            union { _Float16 h[4]; uint2 u; } pk;
            pk.h[0] = (_Float16)v.x; pk.h[1] = (_Float16)v.y;
            pk.h[2] = (_Float16)v.z; pk.h[3] = (_Float16)v.w;
            *(uint2*)(smem + r * 272 + seg * 8) = pk.u;
        }
    }

    f32x4 acc[2][8];
    #pragma unroll
    for (int c = 0; c < 8; ++c) {
        float bc = bias[c * 16 + lm];
        acc[0][c] = (f32x4){bc, bc, bc, bc};
        acc[1][c] = acc[0][c];
    }
    __syncthreads();

    const _Float16* Wt16 = (const _Float16*)Wt;
    #pragma unroll
    for (int kc = 0; kc < 4; ++kc) {
        half8 a0 = *(const half8*)(smem + (wid * 32 + lm) * 272 + kc * 64 + quad * 16);
        half8 a1 = *(const half8*)(smem + (wid * 32 + 16 + lm) * 272 + kc * 64 + quad * 16);
        #pragma unroll
        for (int c = 0; c < 8; ++c) {
            half8 b = *(const half8*)(Wt16 + (c * 16 + lm) * DIMM + kc * 32 + quad * 8);
            acc[0][c] = __builtin_amdgcn_mfma_f32_16x16x32_f16(a0, b, acc[0][c], 0, 0, 0);
            acc[1][c] = __builtin_amdgcn_mfma_f32_16x16x32_f16(a1, b, acc[1][c], 0, 0, 0);
        }
    }

    __syncthreads();
    #pragma unroll
    for (int r = 0; r < 2; ++r)
        #pragma unroll
        for (int c = 0; c < 8; ++c)
            #pragma unroll
            for (int i = 0; i < 4; ++i) {
                int rit = wid * 32 + r * 16 + quad * 4 + i;
                int col = c * 16 + lm;
                *(_Float16*)(smem + rit * 256 + col * 2) = (_Float16)acc[r][c][i];
            }
    __syncthreads();
    for (int i = tid; i < 128 * 16; i += 256) {
        int r = i >> 4, seg = i & 15;
        int gr = row0 + r;
        if (gr < N)
            ((uint4*)(out + (size_t)gr * DIMM))[seg] = ((const uint4*)(smem + r * 256))[seg];
    }
}

// ---------------------------------------------------------------------------
// Aggregate (fp16 gather, fp16 out): wave per node (strided); latency+VALU opt.
//   - 32-edge volleys, 4 edge groups x 16 lanes, clamp+zero-weight for partial
//     slots; PER-SLOT WAVE-UNIFORM GUARDS (e,e1 uniform -> scalar branch) skip
//     empty 4-edge slots entirely: deg-16 nodes run 4 j-steps, not 8 (round-3
//     ran all 8 -> ~2x dummy cvt/FMA, VALUBusy 40%).
//   - CROSS-NODE CSR PIPELINE: next node's first csr volley is issued after
//     this node's FMAs and consumed next iteration -> its latency hides under
//     the shfl-reduce/leaky/stats/store tail. c[8] single-buffered (weights
//     consumed before restage), so no VGPR growth.
//   - Self-loop term only in grp==0 (groups are summed by the shfl reduction).
//   - No min-waves launch bound (round-2: forcing VGPR=32 spilled c[8],
//     WRITE_SIZE 27->670 MB). Zero spill > nominal occupancy.
// ---------------------------------------------------------------------------

__global__ __launch_bounds__(256) void k_agg(const __half* __restrict__ t, __half* __restrict__ out,
                                             const int* __restrict__ rowptr, const int2* __restrict__ csr,
                                             const float* __restrict__ dinv,
                                             float* __restrict__ stats, int N, int nwaves) {
    int tid = threadIdx.x;
    int lane = tid & 63, wid = tid >> 6;
    int grp = lane >> 4;       // edge sub-slot 0..3
    int l16 = lane & 15;       // covers cols [8*l16, 8*l16+8)
    int gw = blockIdx.x * 4 + wid;

    float sx[8] = {0.f, 0.f, 0.f, 0.f, 0.f, 0.f, 0.f, 0.f};
    float qx[8] = {0.f, 0.f, 0.f, 0.f, 0.f, 0.f, 0.f, 0.f};

    int node = gw;
    int e0 = 0, e1 = 0;
    float di = 0.f;
    int2 c[8];
    if (node < N) {
        e0 = rowptr[node]; e1 = rowptr[node + 1]; di = dinv[node];
        int last = e1 - 1;
        #pragma unroll
        for (int j = 0; j < 8; ++j) {
            if (e0 + 4 * j < e1) {                   // wave-uniform guard
                int idx = e0 + 4 * j + grp;
                int idxc = idx < last ? idx : last;  // clamp: always a real edge
                c[j] = csr[idxc];
                if (idx >= e1) c[j].y = 0;           // zero weight for dummies
            }
        }
    }

    while (node < N) {
        // prefetch next node's metadata
        int nxt = node + nwaves;
        int ep0 = 0, ep1 = 0;
        float dip = 0.f;
        if (nxt < N) { ep0 = rowptr[nxt]; ep1 = rowptr[nxt + 1]; dip = dinv[nxt]; }

        // self row: issue now, consume after the edge loop
        union { half8 h; __half2 h2[4]; } us;
        us.h = *(const half8*)(t + ((size_t)(unsigned)node << 7) + l16 * 8);

        float v[8] = {0.f, 0.f, 0.f, 0.f, 0.f, 0.f, 0.f, 0.f};

        // first volley from staged c[]
        #pragma unroll
        for (int j = 0; j < 8; ++j) {
            if (e0 + 4 * j < e1) {
                float wgt = __int_as_float(c[j].y);
                union { half8 h; __half2 h2[4]; } g;
                g.h = *(const half8*)(t + ((size_t)(unsigned)c[j].x << 7) + l16 * 8);
                #pragma unroll
                for (int p = 0; p < 4; ++p) {
                    float2 f = __half22float2(g.h2[p]);
                    v[2 * p]     = fmaf(wgt, f.x, v[2 * p]);
                    v[2 * p + 1] = fmaf(wgt, f.y, v[2 * p + 1]);
                }
            }
        }
        // rare extra volleys (deg > 32), inline staged
        for (int e = e0 + 32; e < e1; e += 32) {
            int last = e1 - 1;
            #pragma unroll
            for (int j = 0; j < 8; ++j) {
                if (e + 4 * j < e1) {
                    int idx = e + 4 * j + grp;
                    int idxc = idx < last ? idx : last;
                    int2 cw = csr[idxc];
                    if (idx >= e1) cw.y = 0;
                    float wgt = __int_as_float(cw.y);
                    union { half8 h; __half2 h2[4]; } g;
                    g.h = *(const half8*)(t + ((size_t)(unsigned)cw.x << 7) + l16 * 8);
                    #pragma unroll
                    for (int p = 0; p < 4; ++p) {
                        float2 f = __half22float2(g.h2[p]);
                        v[2 * p]     = fmaf(wgt, f.x, v[2 * p]);
                        v[2 * p + 1] = fmaf(wgt, f.y, v[2 * p + 1]);
                    }
                }
            }
        }

        // self-loop term — ONLY group 0 (groups are summed by the reduction)
        float sn = (grp == 0) ? di * di : 0.f;
        #pragma unroll
        for (int p = 0; p < 4; ++p) {
            float2 f = __half22float2(us.h2[p]);
            v[2 * p]     = fmaf(sn, f.x, v[2 * p]);
            v[2 * p + 1] = fmaf(sn, f.y, v[2 * p + 1]);
        }

        // stage NEXT node's first csr volley: latency hides under reduce/store
        if (nxt < N) {
            int lastn = ep1 - 1;
            #pragma unroll
            for (int j = 0; j < 8; ++j) {
                if (ep0 + 4 * j < ep1) {
                    int idx = ep0 + 4 * j + grp;
                    int idxc = idx < lastn ? idx : lastn;
                    c[j] = csr[idxc];
                    if (idx >= ep1) c[j].y = 0;
                }
            }
        }

        // combine the 4 group partials
        #pragma unroll
        for (int i = 0; i < 8; ++i) {
            v[i] += __shfl_down(v[i], 32, 64);
            v[i] += __shfl_down(v[i], 16, 64);
        }
        if (grp == 0) {
            union { _Float16 h[8]; uint4 u4; } pk;
            #pragma unroll
            for (int i = 0; i < 8; ++i) {
                v[i] = v[i] > 0.f ? v[i] : LEAKY_S * v[i];
                sx[i] += v[i];
                qx[i] += v[i] * v[i];
                pk.h[i] = (_Float16)v[i];
            }
            *(uint4*)(out + ((size_t)(unsigned)node << 7) + l16 * 8) = pk.u4;
        }

        node = nxt; e0 = ep0; e1 = ep1; di = dip;
    }

    __shared__ float red[4 * 128];
    if (grp == 0) {
        *(float4*)(red + wid * 128 + l16 * 8)     = make_float4(sx[0], sx[1], sx[2], sx[3]);
        *(float4*)(red + wid * 128 + l16 * 8 + 4) = make_float4(sx[4], sx[5], sx[6], sx[7]);
    }
    __syncthreads();
    if (tid < 128) {
        float s = red[tid] + red[128 + tid] + red[256 + tid] + red[384 + tid];
        atomicAdd(&stats[tid], s);
    }
    __syncthreads();
    if (grp == 0) {
        *(float4*)(red + wid * 128 + l16 * 8)     = make_float4(qx[0], qx[1], qx[2], qx[3]);
        *(float4*)(red + wid * 128 + l16 * 8 + 4) = make_float4(qx[4], qx[5], qx[6], qx[7]);
    }
    __syncthreads();
    if (tid < 128) {
        float s = red[tid] + red[128 + tid] + red[256 + tid] + red[384 + tid];
        atomicAdd(&stats[128 + tid], s);
    }
}

// ---------------------------------------------------------------------------
// Pooling (h is fp16; pool accum fp32). Final BN affine computed in poolfin.
// ---------------------------------------------------------------------------

__global__ __launch_bounds__(64) void k_cnt_bs(const int* __restrict__ batch, int* __restrict__ cnt, int N, int G) {
    int g = blockIdx.x * 64 + threadIdx.x;
    if (g >= G) return;
    int lo = 0, hi = N;
    while (lo < hi) { int mid = (lo + hi) >> 1; if (batch[mid] < g) lo = mid + 1; else hi = mid; }
    int lb = lo;
    lo = 0; hi = N;
    while (lo < hi) { int mid = (lo + hi) >> 1; if (batch[mid] <= g) lo = mid + 1; else hi = mid; }
    cnt[g] = lo - lb;
}

__global__ __launch_bounds__(128) void k_pool(const __half* __restrict__ h, const int* __restrict__ batch,
                                              float* __restrict__ pool, int N, int G) {
    const int CHUNK = 128;
    int start = blockIdx.x * CHUNK;
    if (start >= N) return;
    int end = min(start + CHUNK, N);
    int tid = threadIdx.x;
    float acc = 0.f;
    int cur = batch[start];
    for (int n = start; n < end; ++n) {
        int g = batch[n];
        if (g != cur) {
            if ((unsigned)cur < (unsigned)G) atomicAdd(&pool[(size_t)cur * DIMM + tid], acc);
            acc = 0.f; cur = g;
        }
        acc += __half2float(h[(size_t)n * DIMM + tid]);
    }
    if ((unsigned)cur < (unsigned)G) atomicAdd(&pool[(size_t)cur * DIMM + tid], acc);
}

__global__ __launch_bounds__(256) void k_poolfin(const float* __restrict__ pool, const int* __restrict__ cnt,
                                                 const float* __restrict__ stats, const float* __restrict__ gamma,
                                                 const float* __restrict__ beta,
                                                 float* __restrict__ out, int G, float inv_n) {
    int idx = blockIdx.x * 256 + threadIdx.x;
    if (idx < G * DIMM) {
        int g = idx >> 7, c = idx & 127;
        float mu  = stats[c] * inv_n;
        float var = stats[128 + c] * inv_n - mu * mu;
        float a = gamma[c] * rsqrtf(var + EPS_BN);
        float b = beta[c] - mu * a;
        float m = pool[idx] / (float)max(cnt[g], 1);
        out[idx] = a * m + b;
    }
}

// ---------------------------------------------------------------------------

extern "C" void kernel_launch(void* const* d_in, const int* in_sizes, int n_in,
                              void* d_out, int out_size, void* d_ws, size_t ws_size,
                              hipStream_t stream) {
    const float* x      = (const float*)d_in[0];
    const int*   ei     = (const int*)d_in[1];
    const int*   batch  = (const int*)d_in[2];
    const float* Ws     = (const float*)d_in[3];
    const float* bs     = (const float*)d_in[4];
    const float* gammas = (const float*)d_in[5];
    const float* betas  = (const float*)d_in[6];
    float* outp = (float*)d_out;

    int N = in_sizes[2];
    int E = in_sizes[1] / 2;
    int L = in_sizes[3] / (DIMM * DIMM);
    int G = out_size / DIMM;

    const int* srcv = ei;
    const int* dstv = ei + E;

    int nb = (N + 1023) / 1024;

    char* w = (char*)d_ws;
    auto alloc = [&](size_t bytes) { char* p = w; w += (bytes + 511) & ~size_t(511); return p; };
    int*    deg    = (int*)   alloc((size_t)N * 4);
    int*    cursor = (int*)   alloc((size_t)N * 4);
    int*    rowptr = (int*)   alloc((size_t)(N + 1) * 4);
    int*    bsum   = (int*)   alloc((size_t)nb * 4);
    int*    bofs   = (int*)   alloc((size_t)nb * 4);
    int2*   csr    = (int2*)  alloc((size_t)E * 8);
    float*  dinv   = (float*) alloc((size_t)N * 4);
    __half* hA     = (__half*)alloc((size_t)N * DIMM * 2);
    __half* hB     = (__half*)alloc((size_t)N * DIMM * 2);
    __half* Wt     = (__half*)alloc((size_t)L * DIMM * DIMM * 2);
    float*  stats  = (float*) alloc((size_t)L * 256 * 4);
    float*  pool   = (float*) alloc((size_t)G * DIMM * 4);
    int*    cnt    = (int*)   alloc((size_t)G * 4);

    hipMemsetAsync(deg,    0, (size_t)N * 4, stream);
    hipMemsetAsync(cursor, 0, (size_t)N * 4, stream);
    hipMemsetAsync(stats,  0, (size_t)L * 256 * 4, stream);
    hipMemsetAsync(pool,   0, (size_t)G * DIMM * 4, stream);

    float inv_n = 1.0f / (float)N;

    k_wprep<<<dim3(64, L), 256, 0, stream>>>(Ws, Wt);
    k_deg  <<<(E + 255) / 256, 256, 0, stream>>>(dstv, deg, E, N);
    k_dinv <<<(N + 255) / 256, 256, 0, stream>>>(deg, dinv, N);
    k_scanA<<<nb, 256, 0, stream>>>(deg, bsum, N);
    k_scanB<<<1, 64, 0, stream>>>(bsum, bofs, rowptr, nb, N);
    k_scanC<<<nb, 1024, 0, stream>>>(deg, bofs, rowptr, N);
    k_fill <<<(E + 255) / 256, 256, 0, stream>>>(srcv, dstv, rowptr, cursor, dinv, csr, E, N);

    const void* cur_in = (const void*)x;
    int a_half = 0;
    for (int l = 0; l < L; ++l) {
        // BN affine of layer l-1 computed inside k_gemm (a_half gates it)
        const float* st = (l > 0) ? stats + (size_t)(l - 1) * 256 : stats;
        const float* gm = (l > 0) ? gammas + (size_t)(l - 1) * DIMM : gammas;
        const float* bt = (l > 0) ? betas + (size_t)(l - 1) * DIMM : betas;
        k_gemm<<<(N + 127) / 128, 256, 0, stream>>>(cur_in, Wt + (size_t)l * DIMM * DIMM,
                                                    bs + (size_t)l * DIMM, st, gm, bt, hA, N, a_half, inv_n);
        const int nblk = 2048;   // 8192 waves, strided node assignment
        k_agg<<<nblk, 256, 0, stream>>>(hA, hB, rowptr, csr, dinv,
                                        stats + (size_t)l * 256, N, nblk * 4);
        cur_in = (const void*)hB;
        a_half = 1;
    }

    k_cnt_bs<<<(G + 63) / 64, 64, 0, stream>>>(batch, cnt, N, G);
    k_pool<<<(N + 127) / 128, 128, 0, stream>>>(hB, batch, pool, N, G);
    k_poolfin<<<(G * DIMM + 255) / 256, 256, 0, stream>>>(pool, cnt, stats + (size_t)(L - 1) * 256,
                                                          gammas + (size_t)(L - 1) * DIMM,
                                                          betas + (size_t)(L - 1) * DIMM, outp, G, inv_n);
}

// Round 5
// 1166.539 us; speedup vs baseline: 1.1729x; 1.1729x over previous
//
#include <hip/hip_runtime.h>
#include <hip/hip_fp16.h>

#define DIMM 128
#define LEAKY_S 0.01f
#define EPS_BN 1e-5f

typedef _Float16 half8 __attribute__((ext_vector_type(8)));
typedef float f32x4 __attribute__((ext_vector_type(4)));

// ---------------------------------------------------------------------------
// Graph preprocessing: degree -> rowptr (3-phase parallel scan) -> CSR fill
// ---------------------------------------------------------------------------

__global__ __launch_bounds__(256) void k_deg(const int* __restrict__ dst, int* __restrict__ deg, int E, int N) {
    int i = blockIdx.x * 256 + threadIdx.x;
    if (i < E) {
        int d = dst[i];
        if ((unsigned)d < (unsigned)N) atomicAdd(&deg[d], 1);
    }
}

__global__ __launch_bounds__(256) void k_dinv(const int* __restrict__ deg, float* __restrict__ dinv, int N) {
    int i = blockIdx.x * 256 + threadIdx.x;
    if (i < N) dinv[i] = rsqrtf((float)(deg[i] + 1));   // +1 self-loop
}

__global__ __launch_bounds__(256) void k_scanA(const int* __restrict__ deg, int* __restrict__ bsum, int n) {
    __shared__ int ws[4];
    int tid = threadIdx.x, lane = tid & 63, wid = tid >> 6;
    int base = blockIdx.x * 1024;
    int s = 0;
    #pragma unroll
    for (int j = 0; j < 4; ++j) {
        int i = base + j * 256 + tid;
        if (i < n) s += deg[i];
    }
    #pragma unroll
    for (int off = 32; off > 0; off >>= 1) s += __shfl_down(s, (unsigned)off, 64);
    if (lane == 0) ws[wid] = s;
    __syncthreads();
    if (tid == 0) bsum[blockIdx.x] = ws[0] + ws[1] + ws[2] + ws[3];
}

__global__ __launch_bounds__(64) void k_scanB(const int* __restrict__ bsum, int* __restrict__ bofs,
                                              int* __restrict__ rowptr, int nb, int n) {
    if (threadIdx.x == 0) {
        int run = 0;
        for (int j = 0; j < nb; ++j) { bofs[j] = run; run += bsum[j]; }
        rowptr[n] = run;
    }
}

__global__ __launch_bounds__(1024) void k_scanC(const int* __restrict__ deg, const int* __restrict__ bofs,
                                                int* __restrict__ rowptr, int n) {
    __shared__ int wsum[16];
    int tid = threadIdx.x, lane = tid & 63, wid = tid >> 6;
    int i = blockIdx.x * 1024 + tid;
    int v = (i < n) ? deg[i] : 0;
    int s = v;
    #pragma unroll
    for (int off = 1; off < 64; off <<= 1) {
        int t = __shfl_up(s, (unsigned)off, 64);
        if (lane >= off) s += t;
    }
    if (lane == 63) wsum[wid] = s;
    __syncthreads();
    if (wid == 0 && lane < 16) {
        int ws = wsum[lane];
        #pragma unroll
        for (int off = 1; off < 16; off <<= 1) {
            int t = __shfl_up(ws, (unsigned)off, 64);
            if (lane >= off) ws += t;
        }
        wsum[lane] = ws;
    }
    __syncthreads();
    int woff = wid ? wsum[wid - 1] : 0;
    if (i < n) rowptr[i] = bofs[blockIdx.x] + woff + (s - v);
}

__global__ __launch_bounds__(256) void k_fill(const int* __restrict__ src, const int* __restrict__ dst,
                                              const int* __restrict__ rowptr, int* __restrict__ cursor,
                                              const float* __restrict__ dinv,
                                              int2* __restrict__ csr, int E, int N) {
    int i = blockIdx.x * 256 + threadIdx.x;
    if (i < E) {
        int d = dst[i], s = src[i];
        if ((unsigned)d < (unsigned)N && (unsigned)s < (unsigned)N) {
            int pos = atomicAdd(&cursor[d], 1);
            int idx = rowptr[d] + pos;
            csr[idx] = make_int2(s, __float_as_int(dinv[s] * dinv[d]));
        }
    }
}

// ---------------------------------------------------------------------------
// W/BN fold: for layer l, W'[n][k] = f16(a_k * W[k][n]), bias'[n] = bias_n +
// sum_k b_k W[k][n], where (a,b) is the BN affine of the PREVIOUS layer
// (identity for l=0). Replaces both k_wprep and the per-element affine in the
// gemm prologue: (a*x+b)@W + bias == x@W' + bias'.
// Grid: 128 blocks (one per output col n), 128 threads (one per k).
// ---------------------------------------------------------------------------

__global__ __launch_bounds__(128) void k_wbn(const float* __restrict__ W, const float* __restrict__ bias,
                                             const float* __restrict__ stats, const float* __restrict__ gamma,
                                             const float* __restrict__ beta,
                                             __half* __restrict__ Wt, float* __restrict__ bias2,
                                             int ident, float inv_n) {
    __shared__ float red2[2];
    int n = blockIdx.x;
    int k = threadIdx.x;
    float a = 1.f, b = 0.f;
    if (!ident) {
        float mu  = stats[k] * inv_n;
        float var = stats[128 + k] * inv_n - mu * mu;
        a = gamma[k] * rsqrtf(var + EPS_BN);
        b = beta[k] - mu * a;
    }
    float w = W[k * DIMM + n];
    Wt[n * DIMM + k] = __float2half(a * w);
    float p = b * w;
    #pragma unroll
    for (int off = 32; off > 0; off >>= 1) p += __shfl_down(p, (unsigned)off, 64);
    if ((k & 63) == 0) red2[k >> 6] = p;
    __syncthreads();
    if (k == 0) bias2[n] = bias[n] + red2[0] + red2[1];
}

// ---------------------------------------------------------------------------
// MFMA GEMM: out16[N,128] = f16( A @ W' + bias' ).  A is raw fp32 (layer 0)
// or raw fp16 (later layers) -- NO per-element affine (folded into W').
// A tile staged via vector loads + XOR-swizzled ds_write_b128
// (chunk ^= row&7); reads use the same XOR -> both at the b128 bank floor.
// ---------------------------------------------------------------------------

__global__ __launch_bounds__(256) void k_gemm(const void* __restrict__ A, const __half* __restrict__ Wt,
                                              const float* __restrict__ bias2,
                                              __half* __restrict__ out, int N, int a_half) {
    __shared__ char smem[128 * 256];
    int tid = threadIdx.x;
    int lane = tid & 63, wid = tid >> 6;
    int quad = lane >> 4, lm = lane & 15;
    int row0 = blockIdx.x * 128;

    const float*  Af = (const float*)A;
    const __half* Ah = (const __half*)A;
    #pragma unroll
    for (int it = 0; it < 8; ++it) {
        int i = it * 256 + tid;
        int r = i >> 4, c = i & 15;           // row 0..127, 16B-chunk 0..15
        int gr = row0 + r;
        union { _Float16 h[8]; uint4 u; } pk;
        if (gr < N) {
            if (a_half) {
                pk.u = *(const uint4*)(Ah + (size_t)gr * DIMM + c * 8);
            } else {
                float4 f0 = *(const float4*)(Af + (size_t)gr * DIMM + c * 8);
                float4 f1 = *(const float4*)(Af + (size_t)gr * DIMM + c * 8 + 4);
                pk.h[0] = (_Float16)f0.x; pk.h[1] = (_Float16)f0.y;
                pk.h[2] = (_Float16)f0.z; pk.h[3] = (_Float16)f0.w;
                pk.h[4] = (_Float16)f1.x; pk.h[5] = (_Float16)f1.y;
                pk.h[6] = (_Float16)f1.z; pk.h[7] = (_Float16)f1.w;
            }
        } else {
            pk.u = make_uint4(0, 0, 0, 0);
        }
        *(uint4*)(smem + r * 256 + ((c ^ (r & 7)) << 4)) = pk.u;
    }

    f32x4 acc[2][8];
    #pragma unroll
    for (int c = 0; c < 8; ++c) {
        float bc = bias2[c * 16 + lm];
        acc[0][c] = (f32x4){bc, bc, bc, bc};
        acc[1][c] = acc[0][c];
    }
    __syncthreads();

    const _Float16* Wt16 = (const _Float16*)Wt;
    #pragma unroll
    for (int kc = 0; kc < 4; ++kc) {
        // logical chunk = kc*4+quad; rows wid*32+lm and +16 share (row&7)=lm&7
        int sw = ((kc * 4 + quad) ^ (lm & 7)) << 4;
        half8 a0 = *(const half8*)(smem + (wid * 32 + lm) * 256 + sw);
        half8 a1 = *(const half8*)(smem + (wid * 32 + 16 + lm) * 256 + sw);
        #pragma unroll
        for (int c = 0; c < 8; ++c) {
            half8 b = *(const half8*)(Wt16 + (c * 16 + lm) * DIMM + kc * 32 + quad * 8);
            acc[0][c] = __builtin_amdgcn_mfma_f32_16x16x32_f16(a0, b, acc[0][c], 0, 0, 0);
            acc[1][c] = __builtin_amdgcn_mfma_f32_16x16x32_f16(a1, b, acc[1][c], 0, 0, 0);
        }
    }

    __syncthreads();
    #pragma unroll
    for (int r = 0; r < 2; ++r)
        #pragma unroll
        for (int c = 0; c < 8; ++c)
            #pragma unroll
            for (int i = 0; i < 4; ++i) {
                int rit = wid * 32 + r * 16 + quad * 4 + i;
                int col = c * 16 + lm;
                *(_Float16*)(smem + rit * 256 + col * 2) = (_Float16)acc[r][c][i];
            }
    __syncthreads();
    for (int i = tid; i < 128 * 16; i += 256) {
        int r = i >> 4, seg = i & 15;
        int gr = row0 + r;
        if (gr < N)
            ((uint4*)(out + (size_t)gr * DIMM))[seg] = ((const uint4*)(smem + r * 256))[seg];
    }
}

// ---------------------------------------------------------------------------
// Aggregate: EXACT round-3 structure (measured 105.7 us) -- branch-free
// 32-edge volleys (clamp+zero-weight), metadata prefetch, hoisted self row,
// self term only in grp==0, fused BN stats. Round-4's per-slot guards broke
// load batching (load->wait->FMA chains) and regressed 25%: straight-line
// max-MLP code wins in this latency-bound gather loop.
// ---------------------------------------------------------------------------

__global__ __launch_bounds__(256) void k_agg(const __half* __restrict__ t, __half* __restrict__ out,
                                             const int* __restrict__ rowptr, const int2* __restrict__ csr,
                                             const float* __restrict__ dinv,
                                             float* __restrict__ stats, int N, int nwaves) {
    int tid = threadIdx.x;
    int lane = tid & 63, wid = tid >> 6;
    int grp = lane >> 4;       // edge sub-slot 0..3
    int l16 = lane & 15;       // covers cols [8*l16, 8*l16+8)
    int gw = blockIdx.x * 4 + wid;

    float sx[8] = {0.f, 0.f, 0.f, 0.f, 0.f, 0.f, 0.f, 0.f};
    float qx[8] = {0.f, 0.f, 0.f, 0.f, 0.f, 0.f, 0.f, 0.f};

    int node = gw;
    int e0 = 0, e1 = 0;
    float di = 0.f;
    if (node < N) { e0 = rowptr[node]; e1 = rowptr[node + 1]; di = dinv[node]; }

    while (node < N) {
        // prefetch next node's metadata (consumed next iteration)
        int nxt = node + nwaves;
        int ep0 = 0, ep1 = 0;
        float dip = 0.f;
        if (nxt < N) { ep0 = rowptr[nxt]; ep1 = rowptr[nxt + 1]; dip = dinv[nxt]; }

        // self row: issue now, consume after the edge loop
        union { half8 h; __half2 h2[4]; } us;
        us.h = *(const half8*)(t + ((size_t)(unsigned)node << 7) + l16 * 8);

        float v[8] = {0.f, 0.f, 0.f, 0.f, 0.f, 0.f, 0.f, 0.f};

        for (int e = e0; e < e1; e += 32) {   // e,e1 wave-uniform -> scalar branch
            int2 c[8];
            int last = e1 - 1;
            #pragma unroll
            for (int j = 0; j < 8; ++j) {
                int idx = e + 4 * j + grp;
                int idxc = idx < last ? idx : last;   // clamp: always a real edge
                c[j] = csr[idxc];
                if (idx >= e1) c[j].y = 0;           // zero the weight for dummies
            }
            #pragma unroll
            for (int j = 0; j < 8; ++j) {
                float wgt = __int_as_float(c[j].y);
                union { half8 h; __half2 h2[4]; } g;
                g.h = *(const half8*)(t + ((size_t)(unsigned)c[j].x << 7) + l16 * 8);
                #pragma unroll
                for (int p = 0; p < 4; ++p) {
                    float2 f = __half22float2(g.h2[p]);
                    v[2 * p]     = fmaf(wgt, f.x, v[2 * p]);
                    v[2 * p + 1] = fmaf(wgt, f.y, v[2 * p + 1]);
                }
            }
        }

        // self-loop term — ONLY group 0 (groups are summed by the reduction)
        float sn = (grp == 0) ? di * di : 0.f;
        #pragma unroll
        for (int p = 0; p < 4; ++p) {
            float2 f = __half22float2(us.h2[p]);
            v[2 * p]     = fmaf(sn, f.x, v[2 * p]);
            v[2 * p + 1] = fmaf(sn, f.y, v[2 * p + 1]);
        }

        // combine the 4 group partials
        #pragma unroll
        for (int i = 0; i < 8; ++i) {
            v[i] += __shfl_down(v[i], 32, 64);
            v[i] += __shfl_down(v[i], 16, 64);
        }
        if (grp == 0) {
            union { _Float16 h[8]; uint4 u4; } pk;
            #pragma unroll
            for (int i = 0; i < 8; ++i) {
                v[i] = v[i] > 0.f ? v[i] : LEAKY_S * v[i];
                sx[i] += v[i];
                qx[i] += v[i] * v[i];
                pk.h[i] = (_Float16)v[i];
            }
            *(uint4*)(out + ((size_t)(unsigned)node << 7) + l16 * 8) = pk.u4;
        }

        node = nxt; e0 = ep0; e1 = ep1; di = dip;
    }

    __shared__ float red[4 * 128];
    if (grp == 0) {
        *(float4*)(red + wid * 128 + l16 * 8)     = make_float4(sx[0], sx[1], sx[2], sx[3]);
        *(float4*)(red + wid * 128 + l16 * 8 + 4) = make_float4(sx[4], sx[5], sx[6], sx[7]);
    }
    __syncthreads();
    if (tid < 128) {
        float s = red[tid] + red[128 + tid] + red[256 + tid] + red[384 + tid];
        atomicAdd(&stats[tid], s);
    }
    __syncthreads();
    if (grp == 0) {
        *(float4*)(red + wid * 128 + l16 * 8)     = make_float4(qx[0], qx[1], qx[2], qx[3]);
        *(float4*)(red + wid * 128 + l16 * 8 + 4) = make_float4(qx[4], qx[5], qx[6], qx[7]);
    }
    __syncthreads();
    if (tid < 128) {
        float s = red[tid] + red[128 + tid] + red[256 + tid] + red[384 + tid];
        atomicAdd(&stats[128 + tid], s);
    }
}

// ---------------------------------------------------------------------------
// Pooling (h is fp16; pool accum fp32). Final BN affine computed in poolfin.
// ---------------------------------------------------------------------------

__global__ __launch_bounds__(64) void k_cnt_bs(const int* __restrict__ batch, int* __restrict__ cnt, int N, int G) {
    int g = blockIdx.x * 64 + threadIdx.x;
    if (g >= G) return;
    int lo = 0, hi = N;
    while (lo < hi) { int mid = (lo + hi) >> 1; if (batch[mid] < g) lo = mid + 1; else hi = mid; }
    int lb = lo;
    lo = 0; hi = N;
    while (lo < hi) { int mid = (lo + hi) >> 1; if (batch[mid] <= g) lo = mid + 1; else hi = mid; }
    cnt[g] = lo - lb;
}

__global__ __launch_bounds__(128) void k_pool(const __half* __restrict__ h, const int* __restrict__ batch,
                                              float* __restrict__ pool, int N, int G) {
    const int CHUNK = 128;
    int start = blockIdx.x * CHUNK;
    if (start >= N) return;
    int end = min(start + CHUNK, N);
    int tid = threadIdx.x;
    float acc = 0.f;
    int cur = batch[start];
    for (int n = start; n < end; ++n) {
        int g = batch[n];
        if (g != cur) {
            if ((unsigned)cur < (unsigned)G) atomicAdd(&pool[(size_t)cur * DIMM + tid], acc);
            acc = 0.f; cur = g;
        }
        acc += __half2float(h[(size_t)n * DIMM + tid]);
    }
    if ((unsigned)cur < (unsigned)G) atomicAdd(&pool[(size_t)cur * DIMM + tid], acc);
}

__global__ __launch_bounds__(256) void k_poolfin(const float* __restrict__ pool, const int* __restrict__ cnt,
                                                 const float* __restrict__ stats, const float* __restrict__ gamma,
                                                 const float* __restrict__ beta,
                                                 float* __restrict__ out, int G, float inv_n) {
    int idx = blockIdx.x * 256 + threadIdx.x;
    if (idx < G * DIMM) {
        int g = idx >> 7, c = idx & 127;
        float mu  = stats[c] * inv_n;
        float var = stats[128 + c] * inv_n - mu * mu;
        float a = gamma[c] * rsqrtf(var + EPS_BN);
        float b = beta[c] - mu * a;
        float m = pool[idx] / (float)max(cnt[g], 1);
        out[idx] = a * m + b;
    }
}

// ---------------------------------------------------------------------------

extern "C" void kernel_launch(void* const* d_in, const int* in_sizes, int n_in,
                              void* d_out, int out_size, void* d_ws, size_t ws_size,
                              hipStream_t stream) {
    const float* x      = (const float*)d_in[0];
    const int*   ei     = (const int*)d_in[1];
    const int*   batch  = (const int*)d_in[2];
    const float* Ws     = (const float*)d_in[3];
    const float* bs     = (const float*)d_in[4];
    const float* gammas = (const float*)d_in[5];
    const float* betas  = (const float*)d_in[6];
    float* outp = (float*)d_out;

    int N = in_sizes[2];
    int E = in_sizes[1] / 2;
    int L = in_sizes[3] / (DIMM * DIMM);
    int G = out_size / DIMM;

    const int* srcv = ei;
    const int* dstv = ei + E;

    int nb = (N + 1023) / 1024;

    char* w = (char*)d_ws;
    auto alloc = [&](size_t bytes) { char* p = w; w += (bytes + 511) & ~size_t(511); return p; };
    int*    deg    = (int*)   alloc((size_t)N * 4);
    int*    cursor = (int*)   alloc((size_t)N * 4);
    int*    rowptr = (int*)   alloc((size_t)(N + 1) * 4);
    int*    bsum   = (int*)   alloc((size_t)nb * 4);
    int*    bofs   = (int*)   alloc((size_t)nb * 4);
    int2*   csr    = (int2*)  alloc((size_t)E * 8);
    float*  dinv   = (float*) alloc((size_t)N * 4);
    __half* hA     = (__half*)alloc((size_t)N * DIMM * 2);
    __half* hB     = (__half*)alloc((size_t)N * DIMM * 2);
    __half* Wt     = (__half*)alloc((size_t)DIMM * DIMM * 2);   // per-layer, rebuilt by k_wbn
    float*  bias2  = (float*) alloc((size_t)DIMM * 4);
    float*  stats  = (float*) alloc((size_t)L * 256 * 4);
    float*  pool   = (float*) alloc((size_t)G * DIMM * 4);
    int*    cnt    = (int*)   alloc((size_t)G * 4);

    hipMemsetAsync(deg,    0, (size_t)N * 4, stream);
    hipMemsetAsync(cursor, 0, (size_t)N * 4, stream);
    hipMemsetAsync(stats,  0, (size_t)L * 256 * 4, stream);
    hipMemsetAsync(pool,   0, (size_t)G * DIMM * 4, stream);

    float inv_n = 1.0f / (float)N;

    k_deg  <<<(E + 255) / 256, 256, 0, stream>>>(dstv, deg, E, N);
    k_dinv <<<(N + 255) / 256, 256, 0, stream>>>(deg, dinv, N);
    k_scanA<<<nb, 256, 0, stream>>>(deg, bsum, N);
    k_scanB<<<1, 64, 0, stream>>>(bsum, bofs, rowptr, nb, N);
    k_scanC<<<nb, 1024, 0, stream>>>(deg, bofs, rowptr, N);
    k_fill <<<(E + 255) / 256, 256, 0, stream>>>(srcv, dstv, rowptr, cursor, dinv, csr, E, N);

    const void* cur_in = (const void*)x;
    int a_half = 0;
    for (int l = 0; l < L; ++l) {
        // fold BN affine of layer l-1 into W_l / bias_l
        const float* st = (l > 0) ? stats + (size_t)(l - 1) * 256 : stats;
        const float* gm = (l > 0) ? gammas + (size_t)(l - 1) * DIMM : gammas;
        const float* bt = (l > 0) ? betas + (size_t)(l - 1) * DIMM : betas;
        k_wbn<<<DIMM, DIMM, 0, stream>>>(Ws + (size_t)l * DIMM * DIMM, bs + (size_t)l * DIMM,
                                         st, gm, bt, Wt, bias2, (l == 0) ? 1 : 0, inv_n);
        k_gemm<<<(N + 127) / 128, 256, 0, stream>>>(cur_in, Wt, bias2, hA, N, a_half);
        const int nblk = 2048;   // 8192 waves, strided node assignment
        k_agg<<<nblk, 256, 0, stream>>>(hA, hB, rowptr, csr, dinv,
                                        stats + (size_t)l * 256, N, nblk * 4);
        cur_in = (const void*)hB;
        a_half = 1;
    }

    k_cnt_bs<<<(G + 63) / 64, 64, 0, stream>>>(batch, cnt, N, G);
    k_pool<<<(N + 127) / 128, 128, 0, stream>>>(hB, batch, pool, N, G);
    k_poolfin<<<(G * DIMM + 255) / 256, 256, 0, stream>>>(pool, cnt, stats + (size_t)(L - 1) * 256,
                                                          gammas + (size_t)(L - 1) * DIMM,
                                                          betas + (size_t)(L - 1) * DIMM, outp, G, inv_n);
}

// Round 6
// 1084.834 us; speedup vs baseline: 1.2613x; 1.0753x over previous
//
#include <hip/hip_runtime.h>
#include <hip/hip_fp16.h>

#define DIMM 128
#define LEAKY_S 0.01f
#define EPS_BN 1e-5f

typedef _Float16 half8 __attribute__((ext_vector_type(8)));
typedef float f32x4 __attribute__((ext_vector_type(4)));

// ---------------------------------------------------------------------------
// Graph preprocessing: degree -> rowptr (3-phase parallel scan) -> CSR fill
// ---------------------------------------------------------------------------

__global__ __launch_bounds__(256) void k_deg(const int* __restrict__ dst, int* __restrict__ deg, int E, int N) {
    int i = blockIdx.x * 256 + threadIdx.x;
    if (i < E) {
        int d = dst[i];
        if ((unsigned)d < (unsigned)N) atomicAdd(&deg[d], 1);
    }
}

__global__ __launch_bounds__(256) void k_dinv(const int* __restrict__ deg, float* __restrict__ dinv, int N) {
    int i = blockIdx.x * 256 + threadIdx.x;
    if (i < N) dinv[i] = rsqrtf((float)(deg[i] + 1));   // +1 self-loop
}

__global__ __launch_bounds__(256) void k_scanA(const int* __restrict__ deg, int* __restrict__ bsum, int n) {
    __shared__ int ws[4];
    int tid = threadIdx.x, lane = tid & 63, wid = tid >> 6;
    int base = blockIdx.x * 1024;
    int s = 0;
    #pragma unroll
    for (int j = 0; j < 4; ++j) {
        int i = base + j * 256 + tid;
        if (i < n) s += deg[i];
    }
    #pragma unroll
    for (int off = 32; off > 0; off >>= 1) s += __shfl_down(s, (unsigned)off, 64);
    if (lane == 0) ws[wid] = s;
    __syncthreads();
    if (tid == 0) bsum[blockIdx.x] = ws[0] + ws[1] + ws[2] + ws[3];
}

__global__ __launch_bounds__(64) void k_scanB(const int* __restrict__ bsum, int* __restrict__ bofs,
                                              int* __restrict__ rowptr, int nb, int n) {
    if (threadIdx.x == 0) {
        int run = 0;
        for (int j = 0; j < nb; ++j) { bofs[j] = run; run += bsum[j]; }
        rowptr[n] = run;
    }
}

__global__ __launch_bounds__(1024) void k_scanC(const int* __restrict__ deg, const int* __restrict__ bofs,
                                                int* __restrict__ rowptr, int n) {
    __shared__ int wsum[16];
    int tid = threadIdx.x, lane = tid & 63, wid = tid >> 6;
    int i = blockIdx.x * 1024 + tid;
    int v = (i < n) ? deg[i] : 0;
    int s = v;
    #pragma unroll
    for (int off = 1; off < 64; off <<= 1) {
        int t = __shfl_up(s, (unsigned)off, 64);
        if (lane >= off) s += t;
    }
    if (lane == 63) wsum[wid] = s;
    __syncthreads();
    if (wid == 0 && lane < 16) {
        int ws = wsum[lane];
        #pragma unroll
        for (int off = 1; off < 16; off <<= 1) {
            int t = __shfl_up(ws, (unsigned)off, 64);
            if (lane >= off) ws += t;
        }
        wsum[lane] = ws;
    }
    __syncthreads();
    int woff = wid ? wsum[wid - 1] : 0;
    if (i < n) rowptr[i] = bofs[blockIdx.x] + woff + (s - v);
}

__global__ __launch_bounds__(256) void k_fill(const int* __restrict__ src, const int* __restrict__ dst,
                                              const int* __restrict__ rowptr, int* __restrict__ cursor,
                                              const float* __restrict__ dinv,
                                              int2* __restrict__ csr, int E, int N) {
    int i = blockIdx.x * 256 + threadIdx.x;
    if (i < E) {
        int d = dst[i], s = src[i];
        if ((unsigned)d < (unsigned)N && (unsigned)s < (unsigned)N) {
            int pos = atomicAdd(&cursor[d], 1);
            int idx = rowptr[d] + pos;
            csr[idx] = make_int2(s, __float_as_int(dinv[s] * dinv[d]));
        }
    }
}

// ---------------------------------------------------------------------------
// W/BN fold: for layer l, W'[n][k] = f16(a_k * W[k][n]), bias'[n] = bias_n +
// sum_k b_k W[k][n], where (a,b) is the BN affine of the PREVIOUS layer
// (identity for l=0): (a*x+b)@W + bias == x@W' + bias'.
// ---------------------------------------------------------------------------

__global__ __launch_bounds__(128) void k_wbn(const float* __restrict__ W, const float* __restrict__ bias,
                                             const float* __restrict__ stats, const float* __restrict__ gamma,
                                             const float* __restrict__ beta,
                                             __half* __restrict__ Wt, float* __restrict__ bias2,
                                             int ident, float inv_n) {
    __shared__ float red2[2];
    int n = blockIdx.x;
    int k = threadIdx.x;
    float a = 1.f, b = 0.f;
    if (!ident) {
        float mu  = stats[k] * inv_n;
        float var = stats[128 + k] * inv_n - mu * mu;
        a = gamma[k] * rsqrtf(var + EPS_BN);
        b = beta[k] - mu * a;
    }
    float w = W[k * DIMM + n];
    Wt[n * DIMM + k] = __float2half(a * w);
    float p = b * w;
    #pragma unroll
    for (int off = 32; off > 0; off >>= 1) p += __shfl_down(p, (unsigned)off, 64);
    if ((k & 63) == 0) red2[k >> 6] = p;
    __syncthreads();
    if (k == 0) bias2[n] = bias[n] + red2[0] + red2[1];
}

// ---------------------------------------------------------------------------
// MFMA GEMM: out16[N,128] = f16( A @ W' + bias' ).  A raw fp32 (layer 0) or
// raw fp16 (later layers); BN affine folded into W'. XOR-swizzled LDS.
// ---------------------------------------------------------------------------

__global__ __launch_bounds__(256) void k_gemm(const void* __restrict__ A, const __half* __restrict__ Wt,
                                              const float* __restrict__ bias2,
                                              __half* __restrict__ out, int N, int a_half) {
    __shared__ char smem[128 * 256];
    int tid = threadIdx.x;
    int lane = tid & 63, wid = tid >> 6;
    int quad = lane >> 4, lm = lane & 15;
    int row0 = blockIdx.x * 128;

    const float*  Af = (const float*)A;
    const __half* Ah = (const __half*)A;
    #pragma unroll
    for (int it = 0; it < 8; ++it) {
        int i = it * 256 + tid;
        int r = i >> 4, c = i & 15;           // row 0..127, 16B-chunk 0..15
        int gr = row0 + r;
        union { _Float16 h[8]; uint4 u; } pk;
        if (gr < N) {
            if (a_half) {
                pk.u = *(const uint4*)(Ah + (size_t)gr * DIMM + c * 8);
            } else {
                float4 f0 = *(const float4*)(Af + (size_t)gr * DIMM + c * 8);
                float4 f1 = *(const float4*)(Af + (size_t)gr * DIMM + c * 8 + 4);
                pk.h[0] = (_Float16)f0.x; pk.h[1] = (_Float16)f0.y;
                pk.h[2] = (_Float16)f0.z; pk.h[3] = (_Float16)f0.w;
                pk.h[4] = (_Float16)f1.x; pk.h[5] = (_Float16)f1.y;
                pk.h[6] = (_Float16)f1.z; pk.h[7] = (_Float16)f1.w;
            }
        } else {
            pk.u = make_uint4(0, 0, 0, 0);
        }
        *(uint4*)(smem + r * 256 + ((c ^ (r & 7)) << 4)) = pk.u;
    }

    f32x4 acc[2][8];
    #pragma unroll
    for (int c = 0; c < 8; ++c) {
        float bc = bias2[c * 16 + lm];
        acc[0][c] = (f32x4){bc, bc, bc, bc};
        acc[1][c] = acc[0][c];
    }
    __syncthreads();

    const _Float16* Wt16 = (const _Float16*)Wt;
    #pragma unroll
    for (int kc = 0; kc < 4; ++kc) {
        int sw = ((kc * 4 + quad) ^ (lm & 7)) << 4;
        half8 a0 = *(const half8*)(smem + (wid * 32 + lm) * 256 + sw);
        half8 a1 = *(const half8*)(smem + (wid * 32 + 16 + lm) * 256 + sw);
        #pragma unroll
        for (int c = 0; c < 8; ++c) {
            half8 b = *(const half8*)(Wt16 + (c * 16 + lm) * DIMM + kc * 32 + quad * 8);
            acc[0][c] = __builtin_amdgcn_mfma_f32_16x16x32_f16(a0, b, acc[0][c], 0, 0, 0);
            acc[1][c] = __builtin_amdgcn_mfma_f32_16x16x32_f16(a1, b, acc[1][c], 0, 0, 0);
        }
    }

    __syncthreads();
    #pragma unroll
    for (int r = 0; r < 2; ++r)
        #pragma unroll
        for (int c = 0; c < 8; ++c)
            #pragma unroll
            for (int i = 0; i < 4; ++i) {
                int rit = wid * 32 + r * 16 + quad * 4 + i;
                int col = c * 16 + lm;
                *(_Float16*)(smem + rit * 256 + col * 2) = (_Float16)acc[r][c][i];
            }
    __syncthreads();
    for (int i = tid; i < 128 * 16; i += 256) {
        int r = i >> 4, seg = i & 15;
        int gr = row0 + r;
        if (gr < N)
            ((uint4*)(out + (size_t)gr * DIMM))[seg] = ((const uint4*)(smem + r * 256))[seg];
    }
}

// ---------------------------------------------------------------------------
// Aggregate: round-3 branch-free volley structure (measured 103-106 us) PLUS
// cross-node csr prefetch into SEPARATE cn[8] regs:
//   - current node's gathers read addresses from c[] (staged last iteration),
//     so the csr->gather dependency is broken: csr latency for node i+1 hides
//     under node i's gather wait + FMAs + reduce/store tail.
//   - cn stage is branch-free (clamp to [0, e1-1], zero weight for dummies) --
//     round-4 showed per-slot branches destroy load batching.
//   - cn loads are YOUNGER than the gathers in vmcnt order, so the FMA drain
//     does not wait on them.
//   - c <- cn copy at iteration end (16 v_movs, trivial).
//   - VGPR ~84 expected (6 waves/SIMD vs 7): accepted trade for removing a
//     ~400-600cy serial wait per node. No min-waves bound (round-2 spill).
// ---------------------------------------------------------------------------

__global__ __launch_bounds__(256) void k_agg(const __half* __restrict__ t, __half* __restrict__ out,
                                             const int* __restrict__ rowptr, const int2* __restrict__ csr,
                                             const float* __restrict__ dinv,
                                             float* __restrict__ stats, int N, int nwaves) {
    int tid = threadIdx.x;
    int lane = tid & 63, wid = tid >> 6;
    int grp = lane >> 4;       // edge sub-slot 0..3
    int l16 = lane & 15;       // covers cols [8*l16, 8*l16+8)
    int gw = blockIdx.x * 4 + wid;

    float sx[8] = {0.f, 0.f, 0.f, 0.f, 0.f, 0.f, 0.f, 0.f};
    float qx[8] = {0.f, 0.f, 0.f, 0.f, 0.f, 0.f, 0.f, 0.f};

    int node = gw;
    int e0 = 0, e1 = 0;
    float di = 0.f;
    int2 c[8];
    if (node < N) {
        e0 = rowptr[node]; e1 = rowptr[node + 1]; di = dinv[node];
        int last = e1 - 1;
        #pragma unroll
        for (int j = 0; j < 8; ++j) {
            int idx = e0 + 4 * j + grp;
            int idxc = idx < last ? idx : last;
            if (idxc < 0) idxc = 0;              // deg-0 safety
            c[j] = csr[idxc];
            if (idx >= e1) c[j].y = 0;
        }
    }

    while (node < N) {
        // prefetch next node's metadata
        int nxt = node + nwaves;
        int ep0 = 0, ep1 = 0;
        float dip = 0.f;
        if (nxt < N) { ep0 = rowptr[nxt]; ep1 = rowptr[nxt + 1]; dip = dinv[nxt]; }

        // self row: issue now, consume after the edge loop
        union { half8 h; __half2 h2[4]; } us;
        us.h = *(const half8*)(t + ((size_t)(unsigned)node << 7) + l16 * 8);

        float v[8] = {0.f, 0.f, 0.f, 0.f, 0.f, 0.f, 0.f, 0.f};

        // main volley: addresses/weights already staged in c[]
        #pragma unroll
        for (int j = 0; j < 8; ++j) {
            float wgt = __int_as_float(c[j].y);
            union { half8 h; __half2 h2[4]; } g;
            g.h = *(const half8*)(t + ((size_t)(unsigned)c[j].x << 7) + l16 * 8);
            #pragma unroll
            for (int p = 0; p < 4; ++p) {
                float2 f = __half22float2(g.h2[p]);
                v[2 * p]     = fmaf(wgt, f.x, v[2 * p]);
                v[2 * p + 1] = fmaf(wgt, f.y, v[2 * p + 1]);
            }
        }

        // stage NEXT node's first volley into cn (independent -> compiler may
        // hoist these loads under the gather wait; branch-free)
        int2 cn[8];
        {
            int lastn = ep1 - 1;
            #pragma unroll
            for (int j = 0; j < 8; ++j) {
                int idx = ep0 + 4 * j + grp;
                int idxc = idx < lastn ? idx : lastn;
                if (idxc < 0) idxc = 0;          // deg-0 / past-end safety
                cn[j] = csr[idxc];
                if (idx >= ep1) cn[j].y = 0;
            }
        }

        // rare extra volleys (deg > 32), inline staged (round-3 style)
        for (int e = e0 + 32; e < e1; e += 32) {
            int2 cx[8];
            int last = e1 - 1;
            #pragma unroll
            for (int j = 0; j < 8; ++j) {
                int idx = e + 4 * j + grp;
                int idxc = idx < last ? idx : last;
                cx[j] = csr[idxc];
                if (idx >= e1) cx[j].y = 0;
            }
            #pragma unroll
            for (int j = 0; j < 8; ++j) {
                float wgt = __int_as_float(cx[j].y);
                union { half8 h; __half2 h2[4]; } g;
                g.h = *(const half8*)(t + ((size_t)(unsigned)cx[j].x << 7) + l16 * 8);
                #pragma unroll
                for (int p = 0; p < 4; ++p) {
                    float2 f = __half22float2(g.h2[p]);
                    v[2 * p]     = fmaf(wgt, f.x, v[2 * p]);
                    v[2 * p + 1] = fmaf(wgt, f.y, v[2 * p + 1]);
                }
            }
        }

        // self-loop term — ONLY group 0 (groups are summed by the reduction)
        float sn = (grp == 0) ? di * di : 0.f;
        #pragma unroll
        for (int p = 0; p < 4; ++p) {
            float2 f = __half22float2(us.h2[p]);
            v[2 * p]     = fmaf(sn, f.x, v[2 * p]);
            v[2 * p + 1] = fmaf(sn, f.y, v[2 * p + 1]);
        }

        // combine the 4 group partials
        #pragma unroll
        for (int i = 0; i < 8; ++i) {
            v[i] += __shfl_down(v[i], 32, 64);
            v[i] += __shfl_down(v[i], 16, 64);
        }
        if (grp == 0) {
            union { _Float16 h[8]; uint4 u4; } pk;
            #pragma unroll
            for (int i = 0; i < 8; ++i) {
                v[i] = v[i] > 0.f ? v[i] : LEAKY_S * v[i];
                sx[i] += v[i];
                qx[i] += v[i] * v[i];
                pk.h[i] = (_Float16)v[i];
            }
            *(uint4*)(out + ((size_t)(unsigned)node << 7) + l16 * 8) = pk.u4;
        }

        #pragma unroll
        for (int j = 0; j < 8; ++j) c[j] = cn[j];
        node = nxt; e0 = ep0; e1 = ep1; di = dip;
    }

    __shared__ float red[4 * 128];
    if (grp == 0) {
        *(float4*)(red + wid * 128 + l16 * 8)     = make_float4(sx[0], sx[1], sx[2], sx[3]);
        *(float4*)(red + wid * 128 + l16 * 8 + 4) = make_float4(sx[4], sx[5], sx[6], sx[7]);
    }
    __syncthreads();
    if (tid < 128) {
        float s = red[tid] + red[128 + tid] + red[256 + tid] + red[384 + tid];
        atomicAdd(&stats[tid], s);
    }
    __syncthreads();
    if (grp == 0) {
        *(float4*)(red + wid * 128 + l16 * 8)     = make_float4(qx[0], qx[1], qx[2], qx[3]);
        *(float4*)(red + wid * 128 + l16 * 8 + 4) = make_float4(qx[4], qx[5], qx[6], qx[7]);
    }
    __syncthreads();
    if (tid < 128) {
        float s = red[tid] + red[128 + tid] + red[256 + tid] + red[384 + tid];
        atomicAdd(&stats[128 + tid], s);
    }
}

// ---------------------------------------------------------------------------
// Pooling (h is fp16; pool accum fp32). Final BN affine computed in poolfin.
// ---------------------------------------------------------------------------

__global__ __launch_bounds__(64) void k_cnt_bs(const int* __restrict__ batch, int* __restrict__ cnt, int N, int G) {
    int g = blockIdx.x * 64 + threadIdx.x;
    if (g >= G) return;
    int lo = 0, hi = N;
    while (lo < hi) { int mid = (lo + hi) >> 1; if (batch[mid] < g) lo = mid + 1; else hi = mid; }
    int lb = lo;
    lo = 0; hi = N;
    while (lo < hi) { int mid = (lo + hi) >> 1; if (batch[mid] <= g) lo = mid + 1; else hi = mid; }
    cnt[g] = lo - lb;
}

__global__ __launch_bounds__(128) void k_pool(const __half* __restrict__ h, const int* __restrict__ batch,
                                              float* __restrict__ pool, int N, int G) {
    const int CHUNK = 128;
    int start = blockIdx.x * CHUNK;
    if (start >= N) return;
    int end = min(start + CHUNK, N);
    int tid = threadIdx.x;
    float acc = 0.f;
    int cur = batch[start];
    for (int n = start; n < end; ++n) {
        int g = batch[n];
        if (g != cur) {
            if ((unsigned)cur < (unsigned)G) atomicAdd(&pool[(size_t)cur * DIMM + tid], acc);
            acc = 0.f; cur = g;
        }
        acc += __half2float(h[(size_t)n * DIMM + tid]);
    }
    if ((unsigned)cur < (unsigned)G) atomicAdd(&pool[(size_t)cur * DIMM + tid], acc);
}

__global__ __launch_bounds__(256) void k_poolfin(const float* __restrict__ pool, const int* __restrict__ cnt,
                                                 const float* __restrict__ stats, const float* __restrict__ gamma,
                                                 const float* __restrict__ beta,
                                                 float* __restrict__ out, int G, float inv_n) {
    int idx = blockIdx.x * 256 + threadIdx.x;
    if (idx < G * DIMM) {
        int g = idx >> 7, c = idx & 127;
        float mu  = stats[c] * inv_n;
        float var = stats[128 + c] * inv_n - mu * mu;
        float a = gamma[c] * rsqrtf(var + EPS_BN);
        float b = beta[c] - mu * a;
        float m = pool[idx] / (float)max(cnt[g], 1);
        out[idx] = a * m + b;
    }
}

// ---------------------------------------------------------------------------

extern "C" void kernel_launch(void* const* d_in, const int* in_sizes, int n_in,
                              void* d_out, int out_size, void* d_ws, size_t ws_size,
                              hipStream_t stream) {
    const float* x      = (const float*)d_in[0];
    const int*   ei     = (const int*)d_in[1];
    const int*   batch  = (const int*)d_in[2];
    const float* Ws     = (const float*)d_in[3];
    const float* bs     = (const float*)d_in[4];
    const float* gammas = (const float*)d_in[5];
    const float* betas  = (const float*)d_in[6];
    float* outp = (float*)d_out;

    int N = in_sizes[2];
    int E = in_sizes[1] / 2;
    int L = in_sizes[3] / (DIMM * DIMM);
    int G = out_size / DIMM;

    const int* srcv = ei;
    const int* dstv = ei + E;

    int nb = (N + 1023) / 1024;

    char* w = (char*)d_ws;
    auto alloc = [&](size_t bytes) { char* p = w; w += (bytes + 511) & ~size_t(511); return p; };
    int*    deg    = (int*)   alloc((size_t)N * 4);
    int*    cursor = (int*)   alloc((size_t)N * 4);
    int*    rowptr = (int*)   alloc((size_t)(N + 1) * 4);
    int*    bsum   = (int*)   alloc((size_t)nb * 4);
    int*    bofs   = (int*)   alloc((size_t)nb * 4);
    int2*   csr    = (int2*)  alloc((size_t)E * 8);
    float*  dinv   = (float*) alloc((size_t)N * 4);
    __half* hA     = (__half*)alloc((size_t)N * DIMM * 2);
    __half* hB     = (__half*)alloc((size_t)N * DIMM * 2);
    __half* Wt     = (__half*)alloc((size_t)DIMM * DIMM * 2);   // per-layer, rebuilt by k_wbn
    float*  bias2  = (float*) alloc((size_t)DIMM * 4);
    float*  stats  = (float*) alloc((size_t)L * 256 * 4);
    float*  pool   = (float*) alloc((size_t)G * DIMM * 4);
    int*    cnt    = (int*)   alloc((size_t)G * 4);

    hipMemsetAsync(deg,    0, (size_t)N * 4, stream);
    hipMemsetAsync(cursor, 0, (size_t)N * 4, stream);
    hipMemsetAsync(stats,  0, (size_t)L * 256 * 4, stream);
    hipMemsetAsync(pool,   0, (size_t)G * DIMM * 4, stream);

    float inv_n = 1.0f / (float)N;

    k_deg  <<<(E + 255) / 256, 256, 0, stream>>>(dstv, deg, E, N);
    k_dinv <<<(N + 255) / 256, 256, 0, stream>>>(deg, dinv, N);
    k_scanA<<<nb, 256, 0, stream>>>(deg, bsum, N);
    k_scanB<<<1, 64, 0, stream>>>(bsum, bofs, rowptr, nb, N);
    k_scanC<<<nb, 1024, 0, stream>>>(deg, bofs, rowptr, N);
    k_fill <<<(E + 255) / 256, 256, 0, stream>>>(srcv, dstv, rowptr, cursor, dinv, csr, E, N);

    const void* cur_in = (const void*)x;
    int a_half = 0;
    for (int l = 0; l < L; ++l) {
        // fold BN affine of layer l-1 into W_l / bias_l
        const float* st = (l > 0) ? stats + (size_t)(l - 1) * 256 : stats;
        const float* gm = (l > 0) ? gammas + (size_t)(l - 1) * DIMM : gammas;
        const float* bt = (l > 0) ? betas + (size_t)(l - 1) * DIMM : betas;
        k_wbn<<<DIMM, DIMM, 0, stream>>>(Ws + (size_t)l * DIMM * DIMM, bs + (size_t)l * DIMM,
                                         st, gm, bt, Wt, bias2, (l == 0) ? 1 : 0, inv_n);
        k_gemm<<<(N + 127) / 128, 256, 0, stream>>>(cur_in, Wt, bias2, hA, N, a_half);
        const int nblk = 2048;   // 8192 waves, strided node assignment
        k_agg<<<nblk, 256, 0, stream>>>(hA, hB, rowptr, csr, dinv,
                                        stats + (size_t)l * 256, N, nblk * 4);
        cur_in = (const void*)hB;
        a_half = 1;
    }

    k_cnt_bs<<<(G + 63) / 64, 64, 0, stream>>>(batch, cnt, N, G);
    k_pool<<<(N + 127) / 128, 128, 0, stream>>>(hB, batch, pool, N, G);
    k_poolfin<<<(G * DIMM + 255) / 256, 256, 0, stream>>>(pool, cnt, stats + (size_t)(L - 1) * 256,
                                                          gammas + (size_t)(L - 1) * DIMM,
                                                          betas + (size_t)(L - 1) * DIMM, outp, G, inv_n);
}